// Round 18
// baseline (1977.764 us; speedup 1.0000x reference)
//
#include <hip/hip_runtime.h>
#include <hip/hip_bf16.h>

typedef __attribute__((ext_vector_type(8))) short bf16x8v;
typedef __attribute__((ext_vector_type(4))) float f32x4v;

#define DEV __device__ __forceinline__

constexpr int Bn = 8, Sn = 4096, En = 512, Hn = 512;
constexpr int Mn = Bn * Sn;          // 32768 rows
constexpr int NCc = 128, CHc = 32;   // scan: 128 chunks of 32
constexpr size_t SLOT = 33579008;    // = 8*4099*512*2 bytes (padded-conv buffer), 4096-aligned

// ---------- math helpers ----------
DEV float bfu(unsigned u){ union{unsigned v; float f;} c; c.v = u << 16; return c.f; }

DEV void gload16(const void* g, void* l){
  __builtin_amdgcn_global_load_lds((const __attribute__((address_space(1))) void*)g,
                                   (__attribute__((address_space(3))) void*)l, 16, 0, 0);
}

// linear-space gates: f' = (1+e^-i)/(2+e^-f+e^-i), i' = (1+e^-f)/(...), g = x>=0? x+.5 : sigmoid(x)
DEV void gate_lin(float f, float i, float hp, float& fp, float& ig){
  const float ef = __expf(-f);
  const float ei = __expf(-i);
  const float rd = 1.f / (2.f + ef + ei);
  fp = (1.f + ei) * rd;
  const float ipv = (1.f + ef) * rd;
  const float g = (hp >= 0.f) ? (hp + 0.5f) : (1.f / (1.f + __expf(-hp)));
  ig = ipv * g;
}

DEV float g_of(float x){ return (x >= 0.f) ? (x + 0.5f) : (1.f / (1.f + __expf(-x))); }

// ---------- bf16 MFMA GEMM, 256x128 tile, BK=32, 8 waves (4Mx2N), 512 thr ----------
// TLP experiment on r17: 3 LDS buffers -> 2 (72 KB -> 48 KB) = 3 blocks/CU =
// 6 waves/SIMD (was 4). Schedule = T3-minimum (guide m248v2: ~90% of full
// 8-phase): stage(t+1) at tile top, both MFMA phases, ONE combined
// vmcnt(0)+lgkmcnt(0)+s_barrier at tile bottom.
// Hazards: stage(nxt) at top of t overwrites tile t-1's buffer whose reads were
// lgkm-drained before the end-of-(t-1) barrier (WAR). Reads of tile t+1 occur
// after the end-of-t barrier following every wave's own vmcnt(0) (RAW). Load
// cover = 1 tile body (~1000cy) >> L2 latency (~300cy).
// Mechanism: 6 waves/SIMD from 3 desynchronized blocks fill each other's
// stage/wait gaps (m114 co-scheduling; r14->r16 measured +6% from 2->4 waves).
// C[M,N] = A(row-mapped)[M,K] * Bw[N,K]^T + bias
// RES: 0 none, 1 add bf16 residual at res[r*rRS + (r>>12)*rBP + rOff + c]
template<int RES, bool RELU, bool OUTF32>
__global__ __launch_bounds__(512, 6)
void gemm_bf16(const __hip_bfloat16* __restrict__ A,
               const __hip_bfloat16* __restrict__ Bw,
               int N, int K, int aRS, int aBP,
               const float* __restrict__ bias,
               const __hip_bfloat16* __restrict__ res, int rRS, int rBP, int rOff,
               void* __restrict__ out)
{
  __shared__ __align__(16) __hip_bfloat16 Al[2][256][32];   // 32 KB
  __shared__ __align__(16) __hip_bfloat16 Bl[2][128][32];   // 16 KB
  const int tid  = threadIdx.x;
  const int lane = tid & 63;
  const int w    = tid >> 6;            // 0..7
  const int ntn  = N >> 7;
  // T1: XCD-aware bijective swizzle (all grids are multiples of 8)
  const int nwg = gridDim.x;
  int wg = blockIdx.x;
  if ((nwg & 7) == 0) wg = ((wg & 7) * (nwg >> 3)) + (wg >> 3);
  const int bm = wg / ntn, bn = wg % ntn;
  const int rowBase = bm << 8, colBase = bn << 7;
  const int wm = w >> 1, wn = w & 1;    // 4 x 2 wave grid; wave tile 64x64
  const int r0 = lane & 15, kc = lane >> 4;
  const int rc = (kc ^ ((r0 >> 1) & 3)) << 3;   // XOR'd chunk offset within [32k] row

  f32x4v acc[4][4];
  #pragma unroll
  for (int i=0;i<4;i++)
    #pragma unroll
    for (int j=0;j<4;j++)
      #pragma unroll
      for (int q=0;q<4;q++) acc[i][j][q] = 0.f;

  // coalesced staging slots: slot s -> row=s>>2, cp=s&3; src chunk cs=cp^((row>>1)&3)
  const int ar0 = tid >> 2, acp = tid & 3;
  const int ar1 = 128 + ar0;
  const int acs0 = acp ^ ((ar0 >> 1) & 3);
  const int acs1 = acp ^ ((ar1 >> 1) & 3);
  const int rg0 = rowBase + ar0, rg1 = rowBase + ar1;
  const size_t aoff0 = (size_t)rg0*aRS + (size_t)(rg0>>12)*aBP + (acs0<<3);
  const size_t aoff1 = (size_t)rg1*aRS + (size_t)(rg1>>12)*aBP + (acs1<<3);
  const size_t boff  = (size_t)(colBase + ar0)*K + (acs0<<3);

  auto stage = [&](int buf, int t){
    const int ke = t << 5;
    gload16(A  + aoff0 + ke, &Al[buf][ar0][acp<<3]);
    gload16(A  + aoff1 + ke, &Al[buf][ar1][acp<<3]);
    gload16(Bw + boff  + ke, &Bl[buf][ar0][acp<<3]);
  };

  const int NT = K >> 5;                // 16 (K=512) or 64 (K=2048)

  // prologue: stage tile 0, drain, sync
  stage(0, 0);
  asm volatile("s_waitcnt vmcnt(0)" ::: "memory");
  __builtin_amdgcn_s_barrier();

  for (int t=0; t<NT; t++){
    const int cur = t & 1, nxt = cur ^ 1;
    if (t+1 < NT) stage(nxt, t+1);      // issue next-tile loads FIRST
    bf16x8v bfv[4], af[2];
    // ---- p0: m-frags 0,1 ----
    #pragma unroll
    for (int ni=0;ni<4;ni++) bfv[ni] = *(const bf16x8v*)&Bl[cur][(wn<<6)+(ni<<4)+r0][rc];
    af[0] = *(const bf16x8v*)&Al[cur][(wm<<6)+r0][rc];
    af[1] = *(const bf16x8v*)&Al[cur][(wm<<6)+16+r0][rc];
    __builtin_amdgcn_s_setprio(1);
    #pragma unroll
    for (int m=0;m<2;m++)
      #pragma unroll
      for (int ni=0;ni<4;ni++)
        acc[m][ni] = __builtin_amdgcn_mfma_f32_16x16x32_bf16(af[m], bfv[ni], acc[m][ni], 0, 0, 0);
    __builtin_amdgcn_s_setprio(0);
    // ---- p1: m-frags 2,3 ----
    af[0] = *(const bf16x8v*)&Al[cur][(wm<<6)+32+r0][rc];
    af[1] = *(const bf16x8v*)&Al[cur][(wm<<6)+48+r0][rc];
    __builtin_amdgcn_s_setprio(1);
    #pragma unroll
    for (int m=0;m<2;m++)
      #pragma unroll
      for (int ni=0;ni<4;ni++)
        acc[2+m][ni] = __builtin_amdgcn_mfma_f32_16x16x32_bf16(af[m], bfv[ni], acc[2+m][ni], 0, 0, 0);
    __builtin_amdgcn_s_setprio(0);
    // ---- tile end: next tile landed (own vmcnt) + own LDS reads retired ----
    asm volatile("s_waitcnt vmcnt(0) lgkmcnt(0)" ::: "memory");
    __builtin_amdgcn_s_barrier();
  }

  float* outF = (float*)out;
  __hip_bfloat16* outH = (__hip_bfloat16*)out;
  const int q = lane >> 4;
  float bia[4];
  #pragma unroll
  for (int ni=0;ni<4;ni++) bia[ni] = bias[colBase + (wn<<6) + (ni<<4) + r0];
  #pragma unroll
  for (int mi=0;mi<4;mi++){
    const int rb = rowBase + (wm<<6) + (mi<<4) + (q<<2);
    #pragma unroll
    for (int j=0;j<4;j++){
      const int r = rb + j;
      #pragma unroll
      for (int ni=0;ni<4;ni++){        // ni innermost: adjacent 32B chunks per row
        const int c = colBase + (wn<<6) + (ni<<4) + r0;
        float v = acc[mi][ni][j] + bia[ni];
        if constexpr (RES==1) v += __bfloat162float(res[(size_t)r*rRS + (size_t)(r>>12)*rBP + rOff + c]);
        if constexpr (RELU)   v = fmaxf(v, 0.f);
        if constexpr (OUTF32) outF[(size_t)r*N + c] = v;
        else                  outH[(size_t)r*N + c] = __float2bfloat16(v);
      }
    }
  }
}

// ---------- LayerNorm over last dim (512), one block per row, bf16 out ----------
template<bool INF32>
__global__ __launch_bounds__(256)
void ln_k(const void* __restrict__ xin, const float* __restrict__ g, const float* __restrict__ bta,
          __hip_bfloat16* __restrict__ outB, int bBP, int bOff)
{
  const int row = blockIdx.x, tid = threadIdx.x;
  float x0, x1;
  if constexpr (INF32){
    const float2 xv = ((const float2*)((const float*)xin + (size_t)row*En))[tid];
    x0 = xv.x; x1 = xv.y;
  } else {
    const unsigned u = ((const unsigned*)((const __hip_bfloat16*)xin + (size_t)row*En))[tid];
    x0 = bfu(u & 0xffffu); x1 = bfu(u >> 16);
  }
  float s = x0 + x1, sq = x0*x0 + x1*x1;
  #pragma unroll
  for (int off=32; off; off>>=1){ s += __shfl_down(s, off); sq += __shfl_down(sq, off); }
  __shared__ float red[8];
  const int w = tid >> 6, lane = tid & 63;
  if (lane == 0){ red[w] = s; red[4+w] = sq; }
  __syncthreads();
  s  = red[0]+red[1]+red[2]+red[3];
  sq = red[4]+red[5]+red[6]+red[7];
  const float mu   = s * (1.f/En);
  const float rstd = rsqrtf(sq * (1.f/En) - mu*mu + 1e-5f);
  const float2 gv = ((const float2*)g)[tid];
  const float2 bv = ((const float2*)bta)[tid];
  const float y0 = (x0 - mu)*rstd*gv.x + bv.x;
  const float y1 = (x1 - mu)*rstd*gv.y + bv.y;
  const size_t base = (size_t)row*En + (size_t)(row>>12)*bBP + bOff + tid*2;
  __hip_bfloat162 o; o.x = __float2bfloat16(y0); o.y = __float2bfloat16(y1);
  *(__hip_bfloat162*)(outB + base) = o;
}

// ---------- linear-space chunked scan over gates packed [row][1536] = f | i | h~ ----------
__global__ __launch_bounds__(256)
void scan_phaseA(const __hip_bfloat16* __restrict__ gi,
                 float* __restrict__ Aagg, float* __restrict__ Bagg)
{
  const int gid = blockIdx.x*256 + threadIdx.x;        // (b, c, hp)  hp in [0,256)
  const int hp = gid & 255, c = (gid >> 8) & 127, b = gid >> 15;
  size_t base = ((size_t)b*Sn + (size_t)c*CHc)*1536 + 2*hp;
  float A0 = 1.f, B0 = 0.f, A1 = 1.f, B1 = 0.f;
  for (int j=0;j<CHc;j++){
    const size_t idx = base + (size_t)j*1536;
    const unsigned uf = *(const unsigned*)(gi + idx);
    const unsigned ui = *(const unsigned*)(gi + idx + 512);
    const unsigned uh = *(const unsigned*)(gi + idx + 1024);
    float fp, ig;
    gate_lin(bfu(uf & 0xffffu), bfu(ui & 0xffffu), bfu(uh & 0xffffu), fp, ig);
    A0 *= fp; B0 = fp*B0 + ig;
    gate_lin(bfu(uf >> 16), bfu(ui >> 16), bfu(uh >> 16), fp, ig);
    A1 *= fp; B1 = fp*B1 + ig;
  }
  const int o = ((b*NCc + c) << 8) + hp;               // float2 index
  ((float2*)Aagg)[o] = make_float2(A0, A1);
  ((float2*)Bagg)[o] = make_float2(B0, B1);
}

__global__ __launch_bounds__(256)
void scan_phaseB(const float* __restrict__ h0, const float* __restrict__ Aagg,
                 const float* __restrict__ Bagg, float* __restrict__ Vst,
                 float* __restrict__ hlast)
{
  const int gid = blockIdx.x*256 + threadIdx.x;        // b*512 + h
  const int h = gid & 511, b = gid >> 9;
  float v = g_of(h0[gid]);
  for (int c=0;c<NCc;c++){
    const int idx = (b*NCc + c)*Hn + h;
    Vst[idx] = v;
    v = fmaf(Aagg[idx], v, Bagg[idx]);
  }
  hlast[gid] = v;
}

__global__ __launch_bounds__(256)
void scan_phaseC(const __hip_bfloat16* __restrict__ gi, const float* __restrict__ Vst,
                 __hip_bfloat16* __restrict__ hseq)
{
  const int gid = blockIdx.x*256 + threadIdx.x;        // (b, c, hp)
  const int hp = gid & 255, c = (gid >> 8) & 127, b = gid >> 15;
  size_t gbase = ((size_t)b*Sn + (size_t)c*CHc)*1536 + 2*hp;
  size_t obase = ((size_t)b*Sn + (size_t)c*CHc)*Hn  + 2*hp;
  const float2 v2 = ((const float2*)Vst)[((b*NCc + c) << 8) + hp];
  float v0 = v2.x, v1 = v2.y;
  for (int j=0;j<CHc;j++){
    const size_t idx = gbase + (size_t)j*1536;
    const unsigned uf = *(const unsigned*)(gi + idx);
    const unsigned ui = *(const unsigned*)(gi + idx + 512);
    const unsigned uh = *(const unsigned*)(gi + idx + 1024);
    float fp, ig;
    gate_lin(bfu(uf & 0xffffu), bfu(ui & 0xffffu), bfu(uh & 0xffffu), fp, ig);
    v0 = fmaf(fp, v0, ig);
    gate_lin(bfu(uf >> 16), bfu(ui >> 16), bfu(uh >> 16), fp, ig);
    v1 = fmaf(fp, v1, ig);
    __hip_bfloat162 o; o.x = __float2bfloat16(v0); o.y = __float2bfloat16(v1);
    *(__hip_bfloat162*)(hseq + obase + (size_t)j*Hn) = o;
  }
}

// ---------- small utility kernels ----------
__global__ void cvt_f32_bf16(const float* __restrict__ src, __hip_bfloat16* __restrict__ dst, int n){
  const int i = blockIdx.x*256 + threadIdx.x;
  if (i < n) dst[i] = __float2bfloat16(src[i]);
}

// conv_w [O=512][I=512][T=4] f32 -> wcv [O][T*512 + I] bf16
__global__ void conv_pack(const float* __restrict__ src, __hip_bfloat16* __restrict__ dst){
  const int d = blockIdx.x*256 + threadIdx.x;
  const int o = d >> 11, r = d & 2047, tap = r >> 9, i = r & 511;
  dst[d] = __float2bfloat16(src[(o*512 + i)*4 + tap]);
}

__global__ void pad_zero(__hip_bfloat16* __restrict__ padded){
  const int gid = blockIdx.x*256 + threadIdx.x;        // 8*3*512
  if (gid < Bn*3*En){
    const int b = gid / (3*En);
    const int j = gid % (3*En);
    const int which = j >> 9, e = j & 511;
    const int u = (which == 0) ? 0 : (4096 + which);   // rows 0, 4097, 4098
    padded[((size_t)b*(Sn+3) + u)*En + e] = __float2bfloat16(0.f);
  }
}

__global__ void pack_bias3(const float* __restrict__ a, const float* __restrict__ b,
                           const float* __restrict__ c, float* __restrict__ dst){
  const int i = blockIdx.x*256 + threadIdx.x;          // 1536
  if (i < 512)       dst[i] = a[i];
  else if (i < 1024) dst[i] = b[i-512];
  else if (i < 1536) dst[i] = c[i-1024];
}

extern "C" void kernel_launch(void* const* d_in, const int* in_sizes, int n_in,
                              void* d_out, int out_size, void* d_ws, size_t ws_size,
                              hipStream_t stream)
{
  const float* x     = (const float*)d_in[0];
  const float* h0    = (const float*)d_in[1];
  const float* lf_w  = (const float*)d_in[2];
  const float* lf_b  = (const float*)d_in[3];
  const float* li_w  = (const float*)d_in[4];
  const float* li_b  = (const float*)d_in[5];
  const float* lh_w  = (const float*)d_in[6];
  const float* lh_b  = (const float*)d_in[7];
  const float* out_w = (const float*)d_in[8];
  const float* out_b = (const float*)d_in[9];
  const float* conv_w= (const float*)d_in[10];
  const float* conv_b= (const float*)d_in[11];
  const float* ln_g  = (const float*)d_in[12];
  const float* ln_b  = (const float*)d_in[13];
  const float* w1    = (const float*)d_in[14];
  const float* b1    = (const float*)d_in[15];
  const float* w2    = (const float*)d_in[16];
  const float* b2    = (const float*)d_in[17];

  float* outx = (float*)d_out;
  float* outh = outx + (size_t)Mn*En;

  // ---- workspace layout (overlay plan) ----
  const size_t AGG = (size_t)Bn*NCc*Hn*4;              // 2 MB each
  const size_t NEED = 5*SLOT + 3*AGG + 8388608 + 6144;
  if (ws_size < NEED) return;

  char* W = (char*)d_ws;
  __hip_bfloat16* GI   = (__hip_bfloat16*)(W);
  __hip_bfloat16* X2   = (__hip_bfloat16*)(W);
  __hip_bfloat16* G1   = (__hip_bfloat16*)(W + SLOT);
  __hip_bfloat16* X3   = (__hip_bfloat16*)(W + 2*SLOT);
  __hip_bfloat16* HSEQ = (__hip_bfloat16*)(W + 3*SLOT);
  __hip_bfloat16* hmid = (__hip_bfloat16*)(W);
  __hip_bfloat16* XN1  = (__hip_bfloat16*)(W + 4*SLOT);   // later XN3
  float* Aagg = (float*)(W + 5*SLOT);
  float* Bagg = Aagg + (size_t)Bn*NCc*Hn;
  float* Vst  = Bagg + (size_t)Bn*NCc*Hn;
  __hip_bfloat16* wg3  = (__hip_bfloat16*)(Vst + (size_t)Bn*NCc*Hn);
  __hip_bfloat16* wout = wg3  + 1536*512;
  __hip_bfloat16* wcv  = wout + 512*512;
  __hip_bfloat16* wm1  = wcv  + 512*2048;
  __hip_bfloat16* wm2  = wm1  + 2048*512;
  float* bg3 = (float*)(wm2 + 512*2048);

  // weight prep
  cvt_f32_bf16<<<1024, 256, 0, stream>>>(lf_w, wg3,            512*512);
  cvt_f32_bf16<<<1024, 256, 0, stream>>>(li_w, wg3 +  512*512, 512*512);
  cvt_f32_bf16<<<1024, 256, 0, stream>>>(lh_w, wg3 + 1024*512, 512*512);
  cvt_f32_bf16<<<1024, 256, 0, stream>>>(out_w, wout, 512*512);
  cvt_f32_bf16<<<4096, 256, 0, stream>>>(w1, wm1, 2048*512);
  cvt_f32_bf16<<<4096, 256, 0, stream>>>(w2, wm2, 512*2048);
  conv_pack   <<<4096, 256, 0, stream>>>(conv_w, wcv);
  pack_bias3  <<<6,    256, 0, stream>>>(lf_b, li_b, lh_b, bg3);

  // LN1: x(f32) -> XN1 bf16
  ln_k<true><<<Mn, 256, 0, stream>>>(x, ln_g, ln_b, XN1, 0, 0);

  // fused gate GEMM: [Mn,512] x [1536,512]^T -> GI [Mn,1536]   (128 x 12 tiles)
  gemm_bf16<0,false,false><<<1536, 512, 0, stream>>>(XN1, wg3, 1536, 512, 512, 0, bg3, nullptr, 0,0,0, GI);

  // linear-space chunked scan -> HSEQ bf16, h_last f32
  scan_phaseA<<<1024, 256, 0, stream>>>(GI, Aagg, Bagg);
  scan_phaseB<<<16,   256, 0, stream>>>(h0, Aagg, Bagg, Vst, outh);
  scan_phaseC<<<1024, 256, 0, stream>>>(GI, Vst, HSEQ);

  // zero pad rows of G1 (after GI is dead — G1 overlays S1)
  pad_zero<<<48, 256, 0, stream>>>(G1);

  // out-proj + residual(XN1) -> X2 bf16   (128 x 4 tiles)
  gemm_bf16<1,false,false><<<512, 512, 0, stream>>>(HSEQ, wout, 512, 512, 512, 0, out_b, XN1, 512, 0, 0, X2);

  // LN2: X2 -> padded G1 (row t -> padded row t+1)
  ln_k<false><<<Mn, 256, 0, stream>>>(X2, ln_g, ln_b, G1, 3*En, En);

  // conv as K=2048 GEMM over padded rows + residual(xn2 from G1) -> X3 bf16
  gemm_bf16<1,false,false><<<512, 512, 0, stream>>>(G1, wcv, 512, 2048, 512, 3*En, conv_b, G1, 512, 3*En, En, X3);

  // LN3: X3 -> XN3 bf16 (reuses XN1 slot)
  ln_k<false><<<Mn, 256, 0, stream>>>(X3, ln_g, ln_b, XN1, 0, 0);

  // MLP: relu(XN3 @ w1^T) -> hmid (128 x 16 tiles);  hmid @ w2^T + XN3 -> outx (f32)
  gemm_bf16<0,true ,false><<<2048, 512, 0, stream>>>(XN1, wm1, 2048, 512, 512, 0, b1, nullptr, 0,0,0, hmid);
  gemm_bf16<1,false,true ><<<512,  512, 0, stream>>>(hmid, wm2, 512, 2048, 2048, 0, b2, XN1, 512, 0, 0, outx);
}

// Round 19
// 504.410 us; speedup vs baseline: 3.9209x; 3.9209x over previous
//
#include <hip/hip_runtime.h>
#include <hip/hip_bf16.h>

typedef __attribute__((ext_vector_type(8))) short bf16x8v;
typedef __attribute__((ext_vector_type(4))) float f32x4v;

#define DEV __device__ __forceinline__

constexpr int Bn = 8, Sn = 4096, En = 512, Hn = 512;
constexpr int Mn = Bn * Sn;          // 32768 rows
constexpr int NCc = 128, CHc = 32;   // scan: 128 chunks of 32
constexpr size_t SLOT = 33579008;    // = 8*4099*512*2 bytes (padded-conv buffer), 4096-aligned

// ---------- math helpers ----------
DEV float bfu(unsigned u){ union{unsigned v; float f;} c; c.v = u << 16; return c.f; }

DEV void gload16(const void* g, void* l){
  __builtin_amdgcn_global_load_lds((const __attribute__((address_space(1))) void*)g,
                                   (__attribute__((address_space(3))) void*)l, 16, 0, 0);
}

// linear-space gates: f' = (1+e^-i)/(2+e^-f+e^-i), i' = (1+e^-f)/(...), g = x>=0? x+.5 : sigmoid(x)
DEV void gate_lin(float f, float i, float hp, float& fp, float& ig){
  const float ef = __expf(-f);
  const float ei = __expf(-i);
  const float rd = 1.f / (2.f + ef + ei);
  fp = (1.f + ei) * rd;
  const float ipv = (1.f + ef) * rd;
  const float g = (hp >= 0.f) ? (hp + 0.5f) : (1.f / (1.f + __expf(-hp)));
  ig = ipv * g;
}

DEV float g_of(float x){ return (x >= 0.f) ? (x + 0.5f) : (1.f / (1.f + __expf(-x))); }

// ---------- bf16 MFMA GEMM, 256x128 tile, BK=32, 8 waves (4Mx2N), 512 thr ----------
// r18's TLP experiment with the launch-bounds bug fixed: (512,6) capped VGPR at
// ~85 and SPILLED (r18: VGPR=40, WRITE_SIZE 1.6GB of scratch, MfmaUtil 5%).
// (512,4) keeps the r17-verified 56-VGPR allocation; occupancy is then
// LDS-limited: 2 buffers x 48KB -> 3 blocks/CU = 6 waves/SIMD (was 4).
// Schedule = T3-minimum: stage(t+1) at tile top, both MFMA phases, ONE combined
// vmcnt(0)+lgkmcnt(0)+s_barrier at tile bottom.
// Hazards: stage(nxt) at top of t overwrites tile t-1's buffer whose reads were
// lgkm-drained before the end-of-(t-1) barrier (WAR). Reads of tile t+1 occur
// after the end-of-t barrier following every wave's own vmcnt(0) (RAW).
// C[M,N] = A(row-mapped)[M,K] * Bw[N,K]^T + bias
// RES: 0 none, 1 add bf16 residual at res[r*rRS + (r>>12)*rBP + rOff + c]
template<int RES, bool RELU, bool OUTF32>
__global__ __launch_bounds__(512, 4)
void gemm_bf16(const __hip_bfloat16* __restrict__ A,
               const __hip_bfloat16* __restrict__ Bw,
               int N, int K, int aRS, int aBP,
               const float* __restrict__ bias,
               const __hip_bfloat16* __restrict__ res, int rRS, int rBP, int rOff,
               void* __restrict__ out)
{
  __shared__ __align__(16) __hip_bfloat16 Al[2][256][32];   // 32 KB
  __shared__ __align__(16) __hip_bfloat16 Bl[2][128][32];   // 16 KB
  const int tid  = threadIdx.x;
  const int lane = tid & 63;
  const int w    = tid >> 6;            // 0..7
  const int ntn  = N >> 7;
  // T1: XCD-aware bijective swizzle (all grids are multiples of 8)
  const int nwg = gridDim.x;
  int wg = blockIdx.x;
  if ((nwg & 7) == 0) wg = ((wg & 7) * (nwg >> 3)) + (wg >> 3);
  const int bm = wg / ntn, bn = wg % ntn;
  const int rowBase = bm << 8, colBase = bn << 7;
  const int wm = w >> 1, wn = w & 1;    // 4 x 2 wave grid; wave tile 64x64
  const int r0 = lane & 15, kc = lane >> 4;
  const int rc = (kc ^ ((r0 >> 1) & 3)) << 3;   // XOR'd chunk offset within [32k] row

  f32x4v acc[4][4];
  #pragma unroll
  for (int i=0;i<4;i++)
    #pragma unroll
    for (int j=0;j<4;j++)
      #pragma unroll
      for (int q=0;q<4;q++) acc[i][j][q] = 0.f;

  // coalesced staging slots: slot s -> row=s>>2, cp=s&3; src chunk cs=cp^((row>>1)&3)
  const int ar0 = tid >> 2, acp = tid & 3;
  const int ar1 = 128 + ar0;
  const int acs0 = acp ^ ((ar0 >> 1) & 3);
  const int acs1 = acp ^ ((ar1 >> 1) & 3);
  const int rg0 = rowBase + ar0, rg1 = rowBase + ar1;
  const size_t aoff0 = (size_t)rg0*aRS + (size_t)(rg0>>12)*aBP + (acs0<<3);
  const size_t aoff1 = (size_t)rg1*aRS + (size_t)(rg1>>12)*aBP + (acs1<<3);
  const size_t boff  = (size_t)(colBase + ar0)*K + (acs0<<3);

  auto stage = [&](int buf, int t){
    const int ke = t << 5;
    gload16(A  + aoff0 + ke, &Al[buf][ar0][acp<<3]);
    gload16(A  + aoff1 + ke, &Al[buf][ar1][acp<<3]);
    gload16(Bw + boff  + ke, &Bl[buf][ar0][acp<<3]);
  };

  const int NT = K >> 5;                // 16 (K=512) or 64 (K=2048)

  // prologue: stage tile 0, drain, sync
  stage(0, 0);
  asm volatile("s_waitcnt vmcnt(0)" ::: "memory");
  __builtin_amdgcn_s_barrier();

  for (int t=0; t<NT; t++){
    const int cur = t & 1, nxt = cur ^ 1;
    if (t+1 < NT) stage(nxt, t+1);      // issue next-tile loads FIRST
    bf16x8v bfv[4], af[2];
    // ---- p0: m-frags 0,1 ----
    #pragma unroll
    for (int ni=0;ni<4;ni++) bfv[ni] = *(const bf16x8v*)&Bl[cur][(wn<<6)+(ni<<4)+r0][rc];
    af[0] = *(const bf16x8v*)&Al[cur][(wm<<6)+r0][rc];
    af[1] = *(const bf16x8v*)&Al[cur][(wm<<6)+16+r0][rc];
    __builtin_amdgcn_s_setprio(1);
    #pragma unroll
    for (int m=0;m<2;m++)
      #pragma unroll
      for (int ni=0;ni<4;ni++)
        acc[m][ni] = __builtin_amdgcn_mfma_f32_16x16x32_bf16(af[m], bfv[ni], acc[m][ni], 0, 0, 0);
    __builtin_amdgcn_s_setprio(0);
    // ---- p1: m-frags 2,3 ----
    af[0] = *(const bf16x8v*)&Al[cur][(wm<<6)+32+r0][rc];
    af[1] = *(const bf16x8v*)&Al[cur][(wm<<6)+48+r0][rc];
    __builtin_amdgcn_s_setprio(1);
    #pragma unroll
    for (int m=0;m<2;m++)
      #pragma unroll
      for (int ni=0;ni<4;ni++)
        acc[2+m][ni] = __builtin_amdgcn_mfma_f32_16x16x32_bf16(af[m], bfv[ni], acc[2+m][ni], 0, 0, 0);
    __builtin_amdgcn_s_setprio(0);
    // ---- tile end: next tile landed (own vmcnt) + own LDS reads retired ----
    asm volatile("s_waitcnt vmcnt(0) lgkmcnt(0)" ::: "memory");
    __builtin_amdgcn_s_barrier();
  }

  float* outF = (float*)out;
  __hip_bfloat16* outH = (__hip_bfloat16*)out;
  const int q = lane >> 4;
  float bia[4];
  #pragma unroll
  for (int ni=0;ni<4;ni++) bia[ni] = bias[colBase + (wn<<6) + (ni<<4) + r0];
  #pragma unroll
  for (int mi=0;mi<4;mi++){
    const int rb = rowBase + (wm<<6) + (mi<<4) + (q<<2);
    #pragma unroll
    for (int j=0;j<4;j++){
      const int r = rb + j;
      #pragma unroll
      for (int ni=0;ni<4;ni++){        // ni innermost: adjacent 32B chunks per row
        const int c = colBase + (wn<<6) + (ni<<4) + r0;
        float v = acc[mi][ni][j] + bia[ni];
        if constexpr (RES==1) v += __bfloat162float(res[(size_t)r*rRS + (size_t)(r>>12)*rBP + rOff + c]);
        if constexpr (RELU)   v = fmaxf(v, 0.f);
        if constexpr (OUTF32) outF[(size_t)r*N + c] = v;
        else                  outH[(size_t)r*N + c] = __float2bfloat16(v);
      }
    }
  }
}

// ---------- LayerNorm over last dim (512), one block per row, bf16 out ----------
template<bool INF32>
__global__ __launch_bounds__(256)
void ln_k(const void* __restrict__ xin, const float* __restrict__ g, const float* __restrict__ bta,
          __hip_bfloat16* __restrict__ outB, int bBP, int bOff)
{
  const int row = blockIdx.x, tid = threadIdx.x;
  float x0, x1;
  if constexpr (INF32){
    const float2 xv = ((const float2*)((const float*)xin + (size_t)row*En))[tid];
    x0 = xv.x; x1 = xv.y;
  } else {
    const unsigned u = ((const unsigned*)((const __hip_bfloat16*)xin + (size_t)row*En))[tid];
    x0 = bfu(u & 0xffffu); x1 = bfu(u >> 16);
  }
  float s = x0 + x1, sq = x0*x0 + x1*x1;
  #pragma unroll
  for (int off=32; off; off>>=1){ s += __shfl_down(s, off); sq += __shfl_down(sq, off); }
  __shared__ float red[8];
  const int w = tid >> 6, lane = tid & 63;
  if (lane == 0){ red[w] = s; red[4+w] = sq; }
  __syncthreads();
  s  = red[0]+red[1]+red[2]+red[3];
  sq = red[4]+red[5]+red[6]+red[7];
  const float mu   = s * (1.f/En);
  const float rstd = rsqrtf(sq * (1.f/En) - mu*mu + 1e-5f);
  const float2 gv = ((const float2*)g)[tid];
  const float2 bv = ((const float2*)bta)[tid];
  const float y0 = (x0 - mu)*rstd*gv.x + bv.x;
  const float y1 = (x1 - mu)*rstd*gv.y + bv.y;
  const size_t base = (size_t)row*En + (size_t)(row>>12)*bBP + bOff + tid*2;
  __hip_bfloat162 o; o.x = __float2bfloat16(y0); o.y = __float2bfloat16(y1);
  *(__hip_bfloat162*)(outB + base) = o;
}

// ---------- linear-space chunked scan over gates packed [row][1536] = f | i | h~ ----------
__global__ __launch_bounds__(256)
void scan_phaseA(const __hip_bfloat16* __restrict__ gi,
                 float* __restrict__ Aagg, float* __restrict__ Bagg)
{
  const int gid = blockIdx.x*256 + threadIdx.x;        // (b, c, hp)  hp in [0,256)
  const int hp = gid & 255, c = (gid >> 8) & 127, b = gid >> 15;
  size_t base = ((size_t)b*Sn + (size_t)c*CHc)*1536 + 2*hp;
  float A0 = 1.f, B0 = 0.f, A1 = 1.f, B1 = 0.f;
  for (int j=0;j<CHc;j++){
    const size_t idx = base + (size_t)j*1536;
    const unsigned uf = *(const unsigned*)(gi + idx);
    const unsigned ui = *(const unsigned*)(gi + idx + 512);
    const unsigned uh = *(const unsigned*)(gi + idx + 1024);
    float fp, ig;
    gate_lin(bfu(uf & 0xffffu), bfu(ui & 0xffffu), bfu(uh & 0xffffu), fp, ig);
    A0 *= fp; B0 = fp*B0 + ig;
    gate_lin(bfu(uf >> 16), bfu(ui >> 16), bfu(uh >> 16), fp, ig);
    A1 *= fp; B1 = fp*B1 + ig;
  }
  const int o = ((b*NCc + c) << 8) + hp;               // float2 index
  ((float2*)Aagg)[o] = make_float2(A0, A1);
  ((float2*)Bagg)[o] = make_float2(B0, B1);
}

__global__ __launch_bounds__(256)
void scan_phaseB(const float* __restrict__ h0, const float* __restrict__ Aagg,
                 const float* __restrict__ Bagg, float* __restrict__ Vst,
                 float* __restrict__ hlast)
{
  const int gid = blockIdx.x*256 + threadIdx.x;        // b*512 + h
  const int h = gid & 511, b = gid >> 9;
  float v = g_of(h0[gid]);
  for (int c=0;c<NCc;c++){
    const int idx = (b*NCc + c)*Hn + h;
    Vst[idx] = v;
    v = fmaf(Aagg[idx], v, Bagg[idx]);
  }
  hlast[gid] = v;
}

__global__ __launch_bounds__(256)
void scan_phaseC(const __hip_bfloat16* __restrict__ gi, const float* __restrict__ Vst,
                 __hip_bfloat16* __restrict__ hseq)
{
  const int gid = blockIdx.x*256 + threadIdx.x;        // (b, c, hp)
  const int hp = gid & 255, c = (gid >> 8) & 127, b = gid >> 15;
  size_t gbase = ((size_t)b*Sn + (size_t)c*CHc)*1536 + 2*hp;
  size_t obase = ((size_t)b*Sn + (size_t)c*CHc)*Hn  + 2*hp;
  const float2 v2 = ((const float2*)Vst)[((b*NCc + c) << 8) + hp];
  float v0 = v2.x, v1 = v2.y;
  for (int j=0;j<CHc;j++){
    const size_t idx = gbase + (size_t)j*1536;
    const unsigned uf = *(const unsigned*)(gi + idx);
    const unsigned ui = *(const unsigned*)(gi + idx + 512);
    const unsigned uh = *(const unsigned*)(gi + idx + 1024);
    float fp, ig;
    gate_lin(bfu(uf & 0xffffu), bfu(ui & 0xffffu), bfu(uh & 0xffffu), fp, ig);
    v0 = fmaf(fp, v0, ig);
    gate_lin(bfu(uf >> 16), bfu(ui >> 16), bfu(uh >> 16), fp, ig);
    v1 = fmaf(fp, v1, ig);
    __hip_bfloat162 o; o.x = __float2bfloat16(v0); o.y = __float2bfloat16(v1);
    *(__hip_bfloat162*)(hseq + obase + (size_t)j*Hn) = o;
  }
}

// ---------- small utility kernels ----------
__global__ void cvt_f32_bf16(const float* __restrict__ src, __hip_bfloat16* __restrict__ dst, int n){
  const int i = blockIdx.x*256 + threadIdx.x;
  if (i < n) dst[i] = __float2bfloat16(src[i]);
}

// conv_w [O=512][I=512][T=4] f32 -> wcv [O][T*512 + I] bf16
__global__ void conv_pack(const float* __restrict__ src, __hip_bfloat16* __restrict__ dst){
  const int d = blockIdx.x*256 + threadIdx.x;
  const int o = d >> 11, r = d & 2047, tap = r >> 9, i = r & 511;
  dst[d] = __float2bfloat16(src[(o*512 + i)*4 + tap]);
}

__global__ void pad_zero(__hip_bfloat16* __restrict__ padded){
  const int gid = blockIdx.x*256 + threadIdx.x;        // 8*3*512
  if (gid < Bn*3*En){
    const int b = gid / (3*En);
    const int j = gid % (3*En);
    const int which = j >> 9, e = j & 511;
    const int u = (which == 0) ? 0 : (4096 + which);   // rows 0, 4097, 4098
    padded[((size_t)b*(Sn+3) + u)*En + e] = __float2bfloat16(0.f);
  }
}

__global__ void pack_bias3(const float* __restrict__ a, const float* __restrict__ b,
                           const float* __restrict__ c, float* __restrict__ dst){
  const int i = blockIdx.x*256 + threadIdx.x;          // 1536
  if (i < 512)       dst[i] = a[i];
  else if (i < 1024) dst[i] = b[i-512];
  else if (i < 1536) dst[i] = c[i-1024];
}

extern "C" void kernel_launch(void* const* d_in, const int* in_sizes, int n_in,
                              void* d_out, int out_size, void* d_ws, size_t ws_size,
                              hipStream_t stream)
{
  const float* x     = (const float*)d_in[0];
  const float* h0    = (const float*)d_in[1];
  const float* lf_w  = (const float*)d_in[2];
  const float* lf_b  = (const float*)d_in[3];
  const float* li_w  = (const float*)d_in[4];
  const float* li_b  = (const float*)d_in[5];
  const float* lh_w  = (const float*)d_in[6];
  const float* lh_b  = (const float*)d_in[7];
  const float* out_w = (const float*)d_in[8];
  const float* out_b = (const float*)d_in[9];
  const float* conv_w= (const float*)d_in[10];
  const float* conv_b= (const float*)d_in[11];
  const float* ln_g  = (const float*)d_in[12];
  const float* ln_b  = (const float*)d_in[13];
  const float* w1    = (const float*)d_in[14];
  const float* b1    = (const float*)d_in[15];
  const float* w2    = (const float*)d_in[16];
  const float* b2    = (const float*)d_in[17];

  float* outx = (float*)d_out;
  float* outh = outx + (size_t)Mn*En;

  // ---- workspace layout (overlay plan) ----
  const size_t AGG = (size_t)Bn*NCc*Hn*4;              // 2 MB each
  const size_t NEED = 5*SLOT + 3*AGG + 8388608 + 6144;
  if (ws_size < NEED) return;

  char* W = (char*)d_ws;
  __hip_bfloat16* GI   = (__hip_bfloat16*)(W);
  __hip_bfloat16* X2   = (__hip_bfloat16*)(W);
  __hip_bfloat16* G1   = (__hip_bfloat16*)(W + SLOT);
  __hip_bfloat16* X3   = (__hip_bfloat16*)(W + 2*SLOT);
  __hip_bfloat16* HSEQ = (__hip_bfloat16*)(W + 3*SLOT);
  __hip_bfloat16* hmid = (__hip_bfloat16*)(W);
  __hip_bfloat16* XN1  = (__hip_bfloat16*)(W + 4*SLOT);   // later XN3
  float* Aagg = (float*)(W + 5*SLOT);
  float* Bagg = Aagg + (size_t)Bn*NCc*Hn;
  float* Vst  = Bagg + (size_t)Bn*NCc*Hn;
  __hip_bfloat16* wg3  = (__hip_bfloat16*)(Vst + (size_t)Bn*NCc*Hn);
  __hip_bfloat16* wout = wg3  + 1536*512;
  __hip_bfloat16* wcv  = wout + 512*512;
  __hip_bfloat16* wm1  = wcv  + 512*2048;
  __hip_bfloat16* wm2  = wm1  + 2048*512;
  float* bg3 = (float*)(wm2 + 512*2048);

  // weight prep
  cvt_f32_bf16<<<1024, 256, 0, stream>>>(lf_w, wg3,            512*512);
  cvt_f32_bf16<<<1024, 256, 0, stream>>>(li_w, wg3 +  512*512, 512*512);
  cvt_f32_bf16<<<1024, 256, 0, stream>>>(lh_w, wg3 + 1024*512, 512*512);
  cvt_f32_bf16<<<1024, 256, 0, stream>>>(out_w, wout, 512*512);
  cvt_f32_bf16<<<4096, 256, 0, stream>>>(w1, wm1, 2048*512);
  cvt_f32_bf16<<<4096, 256, 0, stream>>>(w2, wm2, 512*2048);
  conv_pack   <<<4096, 256, 0, stream>>>(conv_w, wcv);
  pack_bias3  <<<6,    256, 0, stream>>>(lf_b, li_b, lh_b, bg3);

  // LN1: x(f32) -> XN1 bf16
  ln_k<true><<<Mn, 256, 0, stream>>>(x, ln_g, ln_b, XN1, 0, 0);

  // fused gate GEMM: [Mn,512] x [1536,512]^T -> GI [Mn,1536]   (128 x 12 tiles)
  gemm_bf16<0,false,false><<<1536, 512, 0, stream>>>(XN1, wg3, 1536, 512, 512, 0, bg3, nullptr, 0,0,0, GI);

  // linear-space chunked scan -> HSEQ bf16, h_last f32
  scan_phaseA<<<1024, 256, 0, stream>>>(GI, Aagg, Bagg);
  scan_phaseB<<<16,   256, 0, stream>>>(h0, Aagg, Bagg, Vst, outh);
  scan_phaseC<<<1024, 256, 0, stream>>>(GI, Vst, HSEQ);

  // zero pad rows of G1 (after GI is dead — G1 overlays S1)
  pad_zero<<<48, 256, 0, stream>>>(G1);

  // out-proj + residual(XN1) -> X2 bf16   (128 x 4 tiles)
  gemm_bf16<1,false,false><<<512, 512, 0, stream>>>(HSEQ, wout, 512, 512, 512, 0, out_b, XN1, 512, 0, 0, X2);

  // LN2: X2 -> padded G1 (row t -> padded row t+1)
  ln_k<false><<<Mn, 256, 0, stream>>>(X2, ln_g, ln_b, G1, 3*En, En);

  // conv as K=2048 GEMM over padded rows + residual(xn2 from G1) -> X3 bf16
  gemm_bf16<1,false,false><<<512, 512, 0, stream>>>(G1, wcv, 512, 2048, 512, 3*En, conv_b, G1, 512, 3*En, En, X3);

  // LN3: X3 -> XN3 bf16 (reuses XN1 slot)
  ln_k<false><<<Mn, 256, 0, stream>>>(X3, ln_g, ln_b, XN1, 0, 0);

  // MLP: relu(XN3 @ w1^T) -> hmid (128 x 16 tiles);  hmid @ w2^T + XN3 -> outx (f32)
  gemm_bf16<0,true ,false><<<2048, 512, 0, stream>>>(XN1, wm1, 2048, 512, 512, 0, b1, nullptr, 0,0,0, hmid);
  gemm_bf16<1,false,true ><<<512,  512, 0, stream>>>(hmid, wm2, 512, 2048, 2048, 0, b2, XN1, 512, 0, 0, outx);
}